// Round 14
// baseline (1675.133 us; speedup 1.0000x reference)
//
#include <hip/hip_runtime.h>
#include <math.h>

// MACE-like GNN forward on MI355X, round 8 (6th resubmit — rounds 8-13 never
// ran: GPUAcquisitionTimeout; the in-accumulator-reduction k_message is
// unvalidated).
// Round-7 findings: k_message latency-bound — SQ_LDS_BANK_CONFLICT 5.24M
// (mbuf merge-read 4-way), occupancy 11.7% (VGPR 176 + 38.4KB LDS -> 2
// blocks/CU), 7 barriers/sub-tile; MfmaUtil 9.7 / VALUBusy 17.8 both idle.
// Fix: segmented reduction IN the MFMA accumulator layout (rows = edges):
// per-nbl run-masked sums -> carry regs -> shfl_xor(16,32) cross-group
// reduce -> direct store/atomic to A. mbuf + serial merge + 16 barriers
// deleted; LDS 38.4KB -> ~6KB; __launch_bounds__(256,4) caps VGPR at 128.

#define NN 16384
#define NE 131072
#define NZ 10
#define NG 64

typedef __attribute__((ext_vector_type(8))) short bf16x8;
typedef __attribute__((ext_vector_type(4))) float f32x4;

__device__ __forceinline__ float silu_f(float x) {
    return x / (1.0f + __expf(-x));
}

__device__ __forceinline__ unsigned short f2bf_rne(float x) {
    unsigned int u = __float_as_uint(x);
    unsigned int r = (u + 0x7FFFu + ((u >> 16) & 1u)) >> 16;
    return (unsigned short)r;
}
__device__ __forceinline__ float bf2f(unsigned short b) {
    return __uint_as_float(((unsigned int)b) << 16);
}

// ---- sort by dst: count -> scan -> fill ------------------------------------
__global__ __launch_bounds__(256) void k_count(
    const int* __restrict__ ei, int* __restrict__ deg)
{
    int e = blockIdx.x * 256 + threadIdx.x;
    if (e < NE) atomicAdd(&deg[ei[NE + e]], 1);
}

__global__ __launch_bounds__(256) void k_scan(
    const int* __restrict__ deg, int* __restrict__ cursor)
{
    __shared__ int part[256];
    int t = threadIdx.x;
    int base = t * 64;
    int s = 0;
    for (int i = 0; i < 64; i++) s += deg[base + i];
    part[t] = s;
    __syncthreads();
    for (int off = 1; off < 256; off <<= 1) {
        int v = (t >= off) ? part[t - off] : 0;
        __syncthreads();
        part[t] += v;
        __syncthreads();
    }
    int run = (t > 0) ? part[t - 1] : 0;
    for (int i = 0; i < 64; i++) { cursor[base + i] = run; run += deg[base + i]; }
}

__global__ __launch_bounds__(256) void k_fill(
    const int* __restrict__ ei, int* __restrict__ cursor,
    int* __restrict__ sSrc, int* __restrict__ sDst)
{
    int e = blockIdx.x * 256 + threadIdx.x;
    if (e >= NE) return;
    int d = ei[NE + e];
    int p = atomicAdd(&cursor[d], 1);
    sSrc[p] = ei[e];
    sDst[p] = d;
}

// ---- Wout -> MFMA fragment-linear bf16 hi/lo --------------------------------
__global__ __launch_bounds__(256) void k_wprep(
    const float* __restrict__ Wout, unsigned short* __restrict__ Bh,
    unsigned short* __restrict__ Bl)
{
    int idx = blockIdx.x * 256 + threadIdx.x;     // 16384 total
    int lane = idx & 63;
    int nb = (idx >> 6) & 63;
    int ks = (idx >> 12) & 1;
    int layer = idx >> 13;
    int col = nb * 16 + (lane & 15);
    int tbase = ks * 32 + ((lane >> 4) << 3);
    #pragma unroll
    for (int j = 0; j < 8; j++) {
        float v = Wout[(size_t)layer * 65536 + (size_t)(tbase + j) * 1024 + col];
        unsigned short hi = f2bf_rne(v);
        unsigned short lo = f2bf_rne(v - bf2f(hi));
        Bh[(size_t)idx * 8 + j] = hi;
        Bl[(size_t)idx * 8 + j] = lo;
    }
}

// ---- per-edge geometry ------------------------------------------------------
__global__ __launch_bounds__(256) void k_edge_geom(
    const float* __restrict__ pos, const int* __restrict__ sSrc,
    const int* __restrict__ sDst, float* __restrict__ Y, float* __restrict__ feats)
{
    int e = blockIdx.x * 256 + threadIdx.x;
    if (e >= NE) return;
    int s = sSrc[e];
    int d = sDst[e];
    float vx = pos[d*3+0] - pos[s*3+0];
    float vy = pos[d*3+1] - pos[s*3+1];
    float vz = pos[d*3+2] - pos[s*3+2];
    float len = sqrtf(vx*vx + vy*vy + vz*vz + 1e-12f);
    float inv = 1.0f / len;
    float x = vx*inv, y = vy*inv, z = vz*inv;

    const float s3 = 1.7320508075688772f, s5 = 2.2360679774997896f;
    const float s7 = 2.6457513110645907f, s15 = 3.872983346207417f;
    const float s21 = 4.58257569495584f, s35 = 5.916079783099616f;
    const float s105 = 10.246950765959598f;
    float xx = x*x, yy = y*y, zz = z*z;
    float* Ye = Y + (size_t)e*16;
    Ye[0] = 1.0f;
    Ye[1] = s3*x; Ye[2] = s3*y; Ye[3] = s3*z;
    Ye[4] = s15*x*y; Ye[5] = s15*y*z; Ye[6] = 0.5f*s5*(3.0f*zz - 1.0f);
    Ye[7] = s15*x*z; Ye[8] = 0.5f*s15*(xx - yy);
    Ye[9]  = 0.25f*s35*y*(3.0f*xx - yy);
    Ye[10] = 0.5f*s105*x*y*z;
    Ye[11] = 0.25f*s21*y*(5.0f*zz - 1.0f);
    Ye[12] = 0.5f*s7*z*(5.0f*zz - 3.0f);
    Ye[13] = 0.25f*s21*x*(5.0f*zz - 1.0f);
    Ye[14] = 0.25f*s105*z*(xx - yy);
    Ye[15] = 0.25f*s35*x*(xx - 3.0f*yy);

    float u = len * 0.2f;
    float safe = fmaxf(len, 1e-6f);
    float u5 = u*u; u5 = u5*u5*u;
    float env = 1.0f - 21.0f*u5 + 35.0f*u5*u - 15.0f*u5*u*u;
    env = (u < 1.0f) ? env : 0.0f;
    float c = 0.6324555320336759f * env / safe;   // sqrt(2/5)
    float* fe = feats + (size_t)e*8;
    const float PI = 3.14159265358979323846f;
    #pragma unroll
    for (int n = 1; n <= 8; n++)
        fe[n-1] = c * __sinf((float)n * PI * u);
}

// ---- h init -----------------------------------------------------------------
__global__ __launch_bounds__(256) void k_h_init(
    const float* __restrict__ W_embed, const float* __restrict__ ae,
    const int* __restrict__ species, float* __restrict__ h0,
    float* __restrict__ node_es)
{
    int i = blockIdx.x * 256 + threadIdx.x;   // over N*64
    int n = i >> 6, r = i & 63;
    int sp = species[n];
    h0[i] = W_embed[sp*64 + r];
    if (r == 0) node_es[n] = ae[sp];
}

// ---- radial MLP: feats[8]->64->64->64, one wave per edge -------------------
__global__ __launch_bounds__(256) void k_radial(
    const float* __restrict__ feats, const float* __restrict__ rW1,
    const float* __restrict__ rW2, const float* __restrict__ rW3,
    float* __restrict__ T3)
{
    __shared__ float w1[8*64];
    __shared__ float w2[64*64];
    __shared__ float w3[64*64];
    __shared__ float act[4][64];
    for (int i = threadIdx.x; i < 8*64; i += 256) w1[i] = rW1[i];
    for (int i = threadIdx.x; i < 64*64; i += 256) { w2[i] = rW2[i]; w3[i] = rW3[i]; }
    __syncthreads();
    int wave = threadIdx.x >> 6, lane = threadIdx.x & 63;
    for (int e0 = blockIdx.x * 4; e0 < NE; e0 += gridDim.x * 4) {
        int e = e0 + wave;
        const float* fe = feats + (size_t)e*8;
        float a = 0.f;
        #pragma unroll
        for (int i = 0; i < 8; i++) a = fmaf(fe[i], w1[i*64+lane], a);
        a = silu_f(a);
        act[wave][lane] = a;
        float b = 0.f;
        #pragma unroll
        for (int i = 0; i < 64; i++) b = fmaf(act[wave][i], w2[i*64+lane], b);
        b = silu_f(b);
        act[wave][lane] = b;
        float cc = 0.f;
        #pragma unroll
        for (int i = 0; i < 64; i++) cc = fmaf(act[wave][i], w3[i*64+lane], cc);
        T3[(size_t)e*64 + lane] = silu_f(cc);
    }
}

// ---- message: MFMA + in-accumulator segmented reduction ---------------------
// Block = 256 thr (4 waves) = 64 sorted edges, 4 sub-tiles of 16.
// D layout: col = nb*16 + (lane&15), row(edge) = (lane>>4)*4 + r.
// Per nbl: m[r] = acc[r]*Y*h/8; run-masked row sums accumulate into
// carry[p][nbl]; on run completion: shfl_xor(16)+shfl_xor(32) cross-group
// reduce, lanes 0-15 store (interior run) or atomicAdd (block-boundary run).
__global__ __launch_bounds__(256, 4) void k_message(
    const float* __restrict__ T3, const unsigned short* __restrict__ Bh,
    const unsigned short* __restrict__ Bl, const float* __restrict__ Y,
    const float* __restrict__ h, const int* __restrict__ sSrc,
    const int* __restrict__ sDst, float* __restrict__ A)
{
    __shared__ float hs[16][64];
    __shared__ float ys[16][16];
    __shared__ int srcs[16];
    __shared__ int dall[64];
    __shared__ int runs_s[65];
    __shared__ int runs_d[64];
    __shared__ int nruns_sh;

    int tid = threadIdx.x;
    int lane = tid & 63;
    int w = tid >> 6;
    int gq = lane >> 4;         // row group (0..3)
    int cl = lane & 15;         // col within 16
    int tile0 = blockIdx.x * 64;
    const bf16x8* Bhf = (const bf16x8*)Bh;
    const bf16x8* Blf = (const bf16x8*)Bl;

    // ---- block-wide run table from sorted dst (once) ----
    if (tid < 64) dall[tid] = sDst[tile0 + tid];
    __syncthreads();
    if (tid == 0) {
        int nr = 0, prev = -1;
        for (int e = 0; e < 64; e++) {
            int d = dall[e];
            if (d != prev) { runs_s[nr] = e; runs_d[nr] = d; prev = d; nr++; }
        }
        runs_s[nr] = 64;     // sentinel
        nruns_sh = nr;
    }
    __syncthreads();

    float carry[2][8];
    #pragma unroll
    for (int p = 0; p < 2; p++)
        #pragma unroll
        for (int q = 0; q < 8; q++) carry[p][q] = 0.f;

    int run_lo = 0;

    for (int sb = 0; sb < 4; sb++) {
        int S = sb * 16;
        int g0 = tile0 + S;

        // A fragments from T3 (f32 -> bf16 hi/lo split)
        const float* trow = T3 + (size_t)(g0 + cl) * 64 + (gq << 3);
        float4 p0 = *(const float4*)(trow);
        float4 p1 = *(const float4*)(trow + 4);
        float4 p2 = *(const float4*)(trow + 32);
        float4 p3 = *(const float4*)(trow + 36);
        bf16x8 ah0, al0, ah1, al1;
        {
            float v[16] = {p0.x,p0.y,p0.z,p0.w, p1.x,p1.y,p1.z,p1.w,
                           p2.x,p2.y,p2.z,p2.w, p3.x,p3.y,p3.z,p3.w};
            #pragma unroll
            for (int j = 0; j < 8; j++) {
                unsigned short hi = f2bf_rne(v[j]);
                ah0[j] = (short)hi;
                al0[j] = (short)f2bf_rne(v[j] - bf2f(hi));
            }
            #pragma unroll
            for (int j = 0; j < 8; j++) {
                unsigned short hi = f2bf_rne(v[8+j]);
                ah1[j] = (short)hi;
                al1[j] = (short)f2bf_rne(v[8+j] - bf2f(hi));
            }
        }

        __syncthreads();   // previous sub-tile done reading hs/ys
        if (tid < 16) srcs[tid] = sSrc[g0 + tid];
        __syncthreads();
        {
            int row = tid >> 4, q = tid & 15;
            ((float4*)hs[row])[q] = ((const float4*)(h + (size_t)srcs[row] * 64))[q];
            ys[row][q] = Y[(size_t)(g0 + row) * 16 + q];
        }
        __syncthreads();

        float hv[4][4];
        #pragma unroll
        for (int r = 0; r < 4; r++)
            #pragma unroll
            for (int m4 = 0; m4 < 4; m4++)
                hv[r][m4] = hs[gq*4 + r][m4*16 + cl];

        // first run overlapping this sub-tile (uniform)
        while (runs_s[run_lo + 1] <= S) run_lo++;

        #pragma unroll
        for (int p = 0; p < 2; p++) {
            float yv[4][2];
            #pragma unroll
            for (int r = 0; r < 4; r++)
                #pragma unroll
                for (int kk = 0; kk < 2; kk++)
                    yv[r][kk] = ys[gq*4 + r][p*8 + w*2 + kk] * 0.125f;

            #pragma unroll
            for (int nbl = 0; nbl < 8; nbl++) {
                int nb = p*32 + w*8 + nbl;
                bf16x8 bh0 = Bhf[(0*64 + nb)*64 + lane];
                bf16x8 bl0 = Blf[(0*64 + nb)*64 + lane];
                bf16x8 bh1 = Bhf[(1*64 + nb)*64 + lane];
                bf16x8 bl1 = Blf[(1*64 + nb)*64 + lane];
                f32x4 acc = {0.f, 0.f, 0.f, 0.f};
                acc = __builtin_amdgcn_mfma_f32_16x16x32_bf16(ah0, bh0, acc, 0, 0, 0);
                acc = __builtin_amdgcn_mfma_f32_16x16x32_bf16(al0, bh0, acc, 0, 0, 0);
                acc = __builtin_amdgcn_mfma_f32_16x16x32_bf16(ah0, bl0, acc, 0, 0, 0);
                acc = __builtin_amdgcn_mfma_f32_16x16x32_bf16(ah1, bh1, acc, 0, 0, 0);
                acc = __builtin_amdgcn_mfma_f32_16x16x32_bf16(al1, bh1, acc, 0, 0, 0);
                acc = __builtin_amdgcn_mfma_f32_16x16x32_bf16(ah1, bl1, acc, 0, 0, 0);

                float m0 = acc[0] * yv[0][nbl >> 2] * hv[0][nbl & 3];
                float m1 = acc[1] * yv[1][nbl >> 2] * hv[1][nbl & 3];
                float m2 = acc[2] * yv[2][nbl >> 2] * hv[2][nbl & 3];
                float m3 = acc[3] * yv[3][nbl >> 2] * hv[3][nbl & 3];
                int base = gq * 4;

                int ri = run_lo;
                #pragma unroll 1
                while (runs_s[ri] < S + 16) {
                    int s = runs_s[ri] - S;          // may be <0 (carried run)
                    int e = runs_s[ri + 1] - S;      // may be >16 (continues)
                    float part = 0.f;
                    part += (base+0 >= s && base+0 < e) ? m0 : 0.f;
                    part += (base+1 >= s && base+1 < e) ? m1 : 0.f;
                    part += (base+2 >= s && base+2 < e) ? m2 : 0.f;
                    part += (base+3 >= s && base+3 < e) ? m3 : 0.f;
                    carry[p][nbl] += part;
                    if (e <= 16) {
                        // run completes in this sub-tile: cross-group reduce + flush
                        float t = carry[p][nbl];
                        t += __shfl_xor(t, 16, 64);
                        t += __shfl_xor(t, 32, 64);
                        carry[p][nbl] = 0.f;
                        if (lane < 16) {
                            int gs = runs_s[ri];
                            int ge = runs_s[ri + 1];
                            float* Ap = A + (size_t)runs_d[ri] * 1024 + nb * 16 + cl;
                            if (gs == 0 || ge == 64) atomicAdd(Ap, t);
                            else *Ap = t;
                        }
                        ri++;
                    } else {
                        break;   // run continues into next sub-tile: keep carry
                    }
                }
            }
        }
    }
}

// ---- l=0 node update --------------------------------------------------------
__global__ __launch_bounds__(256) void k_update0(
    const float* __restrict__ A, const float* __restrict__ h0,
    const float* __restrict__ Wsc, const float* __restrict__ pw,
    const float* __restrict__ read1_w, const int* __restrict__ species,
    float* __restrict__ h2, float* __restrict__ node_es)
{
    __shared__ float h0s[4][64];
    int wave = threadIdx.x >> 6, lane = threadIdx.x & 63;
    int n = blockIdx.x * 4 + wave;
    h0s[wave][lane] = h0[(size_t)n*64 + lane];
    __syncthreads();
    int sp = species[n];
    const float* W = Wsc + (size_t)sp*4096;
    float sc0 = 0.f;
    #pragma unroll
    for (int c = 0; c < 64; c++) sc0 = fmaf(h0s[wave][c], W[c*64+lane], sc0);
    float a[16], inv2 = 0.f;
    #pragma unroll
    for (int kk = 0; kk < 16; kk++) {
        a[kk] = A[(size_t)n*1024 + kk*64 + lane];
        inv2 = fmaf(a[kk], a[kk], inv2);
    }
    float inv3 = inv2 * a[0];
    float hn0 = a[0]*pw[lane] + inv2*pw[64+lane] + inv3*pw[128+lane] + sc0;
    h2[(size_t)n*64 + lane] = hn0;
    float r = hn0 * read1_w[lane];
    #pragma unroll
    for (int off = 32; off; off >>= 1) r += __shfl_down(r, off, 64);
    if (lane == 0) node_es[n] += r;
}

// ---- l=1: only readout contribution ----------------------------------------
__global__ __launch_bounds__(256) void k_update1(
    const float* __restrict__ A, const float* __restrict__ h2,
    const float* __restrict__ Wsc, const float* __restrict__ pw,
    const float* __restrict__ Wa, const float* __restrict__ wb,
    const int* __restrict__ species, float* __restrict__ node_es)
{
    __shared__ float h0s[4][64];
    __shared__ float hns[4][64];
    int wave = threadIdx.x >> 6, lane = threadIdx.x & 63;
    int n = blockIdx.x * 4 + wave;
    h0s[wave][lane] = h2[(size_t)n*64 + lane];
    __syncthreads();
    int sp = species[n];
    const float* W = Wsc + (size_t)sp*4096;
    float sc0 = 0.f;
    #pragma unroll
    for (int c = 0; c < 64; c++) sc0 = fmaf(h0s[wave][c], W[c*64+lane], sc0);
    float a[16], inv2 = 0.f;
    #pragma unroll
    for (int kk = 0; kk < 16; kk++) {
        a[kk] = A[(size_t)n*1024 + kk*64 + lane];
        inv2 = fmaf(a[kk], a[kk], inv2);
    }
    float inv3 = inv2 * a[0];
    float hn0 = a[0]*pw[lane] + inv2*pw[64+lane] + inv3*pw[128+lane] + sc0;
    hns[wave][lane] = hn0;
    __syncthreads();
    float contrib = 0.f;
    if (lane < 16) {
        float aj = 0.f;
        #pragma unroll
        for (int f = 0; f < 64; f++) aj = fmaf(hns[wave][f], Wa[f*16+lane], aj);
        contrib = silu_f(aj) * wb[lane];
    }
    #pragma unroll
    for (int off = 8; off; off >>= 1) contrib += __shfl_down(contrib, off, 64);
    if (lane == 0) node_es[n] += contrib;
}

__global__ __launch_bounds__(256) void k_reduce(
    const float* __restrict__ node_es, const int* __restrict__ batch,
    float* __restrict__ out)
{
    __shared__ float bins[NG];
    if (threadIdx.x < NG) bins[threadIdx.x] = 0.f;
    __syncthreads();
    for (int n = blockIdx.x*256 + threadIdx.x; n < NN; n += gridDim.x*256)
        atomicAdd(&bins[batch[n]], node_es[n]);
    __syncthreads();
    if (threadIdx.x < NG) atomicAdd(&out[threadIdx.x], bins[threadIdx.x]);
}

extern "C" void kernel_launch(void* const* d_in, const int* in_sizes, int n_in,
                              void* d_out, int out_size, void* d_ws, size_t ws_size,
                              hipStream_t stream)
{
    const float* positions = (const float*)d_in[0];
    const float* atomic_energies = (const float*)d_in[1];
    const float* W_embed  = (const float*)d_in[2];
    const float* rW1      = (const float*)d_in[3];
    const float* rW2      = (const float*)d_in[4];
    const float* rW3      = (const float*)d_in[5];
    const float* rWout    = (const float*)d_in[6];
    const float* Wsc      = (const float*)d_in[7];
    const float* pw       = (const float*)d_in[8];
    const float* read1_w  = (const float*)d_in[9];
    const float* read2_Wa = (const float*)d_in[10];
    const float* read2_wb = (const float*)d_in[11];
    const int* species    = (const int*)d_in[12];
    const int* edge_index = (const int*)d_in[13];
    const int* batch      = (const int*)d_in[14];
    float* out = (float*)d_out;

    char* w = (char*)d_ws;
    float* Y     = (float*)w;  w += (size_t)NE*16*4;
    float* feats = (float*)w;  w += (size_t)NE*8*4;
    float* T3    = (float*)w;  w += (size_t)NE*64*4;
    float* h0    = (float*)w;  w += (size_t)NN*64*4;
    float* h2    = (float*)w;  w += (size_t)NN*64*4;
    float* A     = (float*)w;  w += (size_t)NN*1024*4;
    float* node_es = (float*)w; w += (size_t)NN*4;
    int* deg     = (int*)w;    w += (size_t)NN*4;
    int* cursor  = (int*)w;    w += (size_t)NN*4;
    int* sSrc    = (int*)w;    w += (size_t)NE*4;
    int* sDst    = (int*)w;    w += (size_t)NE*4;
    unsigned short* Bh = (unsigned short*)w; w += (size_t)2*8192*8*2;
    unsigned short* Bl = (unsigned short*)w; w += (size_t)2*8192*8*2;

    // ---- counting sort by dst
    hipMemsetAsync(deg, 0, (size_t)NN*4, stream);
    k_count<<<NE/256, 256, 0, stream>>>(edge_index, deg);
    k_scan<<<1, 256, 0, stream>>>(deg, cursor);
    k_fill<<<NE/256, 256, 0, stream>>>(edge_index, cursor, sSrc, sDst);

    k_wprep<<<64, 256, 0, stream>>>(rWout, Bh, Bl);
    k_edge_geom<<<NE/256, 256, 0, stream>>>(positions, sSrc, sDst, Y, feats);
    k_h_init<<<NN*64/256, 256, 0, stream>>>(W_embed, atomic_energies, species, h0, node_es);

    // layer 0
    hipMemsetAsync(A, 0, (size_t)NN*1024*4, stream);
    k_radial<<<2048, 256, 0, stream>>>(feats, rW1, rW2, rW3, T3);
    k_message<<<NE/64, 256, 0, stream>>>(T3, Bh, Bl, Y, h0, sSrc, sDst, A);
    k_update0<<<NN/4, 256, 0, stream>>>(A, h0, Wsc, pw, read1_w, species, h2, node_es);

    // layer 1
    hipMemsetAsync(A, 0, (size_t)NN*1024*4, stream);
    k_radial<<<2048, 256, 0, stream>>>(feats, rW1 + 8*64, rW2 + 64*64, rW3 + 64*64, T3);
    k_message<<<NE/64, 256, 0, stream>>>(T3, Bh + (size_t)8192*8, Bl + (size_t)8192*8,
                                         Y, h2, sSrc, sDst, A);
    k_update1<<<NN/4, 256, 0, stream>>>(A, h2, Wsc + 10*4096, pw + 192,
                                        read2_Wa, read2_wb, species, node_es);

    hipMemsetAsync(d_out, 0, NG*sizeof(float), stream);
    k_reduce<<<64, 256, 0, stream>>>(node_es, batch, out);
}